// Round 8
// baseline (745.039 us; speedup 1.0000x reference)
//
#include <hip/hip_runtime.h>

#define SEQ   120
#define WARM  96
#define FLEN  24
#define HDIM  256

typedef __attribute__((ext_vector_type(8))) short bf16x8;
typedef __attribute__((ext_vector_type(4))) float floatx4;
typedef __attribute__((ext_vector_type(4))) unsigned int uintx4;
typedef unsigned int uint;
typedef unsigned long long ull;

// ws layout (bytes):
//   WHI  [0, 512K)        bf16 frag-linear W-hi
//   WLO  [512K, 1M)       bf16 frag-linear W-lo
//   BB   [1M, +4K)        f32 b_ih+b_hh
//   WI   [1M+4K, +4K)     f32 W_ih col
//   BAR  [1M+8K, +8K)     uint bar[32], stride 64 uints (256 B)
//                         +0: step barrier, +16: init barrier, +32..39: xcc ids
//   HG   [1M+16K, +4M)    uint h packed (hi<<16|lo), 2 parities x 32 rg x 16384
//                         frag-linear: idx = (((rt*8+kt)*4+kq)*16+rlow)*8+kk
//   XT   [5M+16K, +960K)  f32 x transposed [t][row]
#define WHI_OFF 0
#define WLO_OFF (512 * 1024)
#define BB_OFF  (1024 * 1024)
#define WI_OFF  (1024 * 1024 + 4096)
#define BAR_OFF (1024 * 1024 + 8192)
#define HG_OFF  (1024 * 1024 + 16384)
#define HG_PAR  524288              // uints per parity
#define XT_OFF  (HG_OFF + 4 * 1024 * 1024)

#define LDS_BYTES 66816             // wlo 64K | fcw 1K | y 256B

__device__ __forceinline__ short f2bf(float v) {
    unsigned u = __float_as_uint(v);
    u += 0x7FFF + ((u >> 16) & 1);              // RNE
    return (short)(u >> 16);
}
__device__ __forceinline__ float bf2f(short s) {
    return __uint_as_float(((unsigned)(unsigned short)s) << 16);
}
__device__ __forceinline__ float fast_rcp(float x) {
    return __builtin_amdgcn_rcpf(x);
}
__device__ __forceinline__ float fast_sig(float x) {
    return fast_rcp(1.0f + __expf(-x));
}
__device__ __forceinline__ float fast_tanh(float x) {
    return 1.0f - 2.0f * fast_rcp(__expf(2.0f * x) + 1.0f);
}

// ---- LLC-coherent (cross-XCD) helpers: agent scope -> device SC bits ----
__device__ __forceinline__ uint load_llc32u(const uint* p) {
    return __hip_atomic_load(p, __ATOMIC_RELAXED, __HIP_MEMORY_SCOPE_AGENT);
}
__device__ __forceinline__ void store_llc32(uint* p, uint v) {
    __hip_atomic_store(p, v, __ATOMIC_RELAXED, __HIP_MEMORY_SCOPE_AGENT);
}

// XCC (XCD) id of the CU executing this wave [measured: learn_hip m09]
__device__ __forceinline__ uint get_xcc_id() {
    uint x;
    asm volatile("s_getreg_b32 %0, hwreg(HW_REG_XCC_ID)" : "=s"(x));
    return x;
}

// ---- direct frag-load pipeline primitives ----
// LOC: sc0 (bypass stale L1, served by shared L2).  !LOC: sc0 sc1 (LLC).
template<bool LOC>
__device__ __forceinline__ void frag_issue(uintx4& d0, uintx4& d1, const uint* p) {
    if constexpr (LOC) {
        asm volatile("global_load_dwordx4 %0, %1, off sc0" : "=v"(d0) : "v"(p));
        asm volatile("global_load_dwordx4 %0, %1, off sc0" : "=v"(d1) : "v"(p + 4));
    } else {
        asm volatile("global_load_dwordx4 %0, %1, off sc0 sc1" : "=v"(d0) : "v"(p));
        asm volatile("global_load_dwordx4 %0, %1, off sc0 sc1" : "=v"(d1) : "v"(p + 4));
    }
}
// counted wait, dataflow-tied to the consumed pair ("+v": consumers cannot be
// hoisted past the wait — rule-18 fix pattern). vmcnt decrements in issue
// order; the kt region contains no compiler VMEM, so the counts are exact.
// n is constant after full unroll -> switch folds to a single s_waitcnt.
__device__ __forceinline__ void frag_waitN(int n, uintx4& d0, uintx4& d1) {
    switch (n) {
    case 14: asm volatile("s_waitcnt vmcnt(14)" : "+v"(d0), "+v"(d1) :: "memory"); break;
    case 12: asm volatile("s_waitcnt vmcnt(12)" : "+v"(d0), "+v"(d1) :: "memory"); break;
    case 10: asm volatile("s_waitcnt vmcnt(10)" : "+v"(d0), "+v"(d1) :: "memory"); break;
    case 8:  asm volatile("s_waitcnt vmcnt(8)"  : "+v"(d0), "+v"(d1) :: "memory"); break;
    case 6:  asm volatile("s_waitcnt vmcnt(6)"  : "+v"(d0), "+v"(d1) :: "memory"); break;
    case 4:  asm volatile("s_waitcnt vmcnt(4)"  : "+v"(d0), "+v"(d1) :: "memory"); break;
    case 2:  asm volatile("s_waitcnt vmcnt(2)"  : "+v"(d0), "+v"(d1) :: "memory"); break;
    default: asm volatile("s_waitcnt vmcnt(0)"  : "+v"(d0), "+v"(d1) :: "memory"); break;
    }
}

union pack16 { uint u[4]; bf16x8 v; };
union upk4   { uintx4 u; float4 f; };

__global__ __launch_bounds__(256) void lstm_prep(
    const float* __restrict__ W_ih, const float* __restrict__ W_hh,
    const float* __restrict__ b_ih, const float* __restrict__ b_hh,
    const float* __restrict__ h0, const float* __restrict__ x,
    unsigned char* __restrict__ ws)
{
    int tid = blockIdx.x * 256 + threadIdx.x;       // grid 2048*256 = 524288
    if (tid < 262144) {
        int col = tid >> 8, k = tid & 255;          // col = gate*256+unit
        float v  = W_hh[tid];
        short hi = f2bf(v);
        short lo = f2bf(v - bf2f(hi));
        int g = col >> 8, rem = col & 255;
        int s = rem >> 5, uo = rem & 31, uc = uo >> 4, n = uo & 15;
        int kt = k >> 5, kq = (k >> 3) & 3, j = k & 7;
        size_t unit = ((((size_t)(s * 2 + uc) * 4 + g) * 8 + kt) * 64 + kq * 16 + n);
        ((short*)(ws + WHI_OFF))[unit * 8 + j] = hi;
        ((short*)(ws + WLO_OFF))[unit * 8 + j] = lo;
    }
    if (tid < 524288) {                              // pack h0 -> parity 0
        int row = tid >> 8, k = tid & 255;
        float v  = h0[tid];
        short hi = f2bf(v);
        short lo = f2bf(v - bf2f(hi));
        int rg = row >> 6, rt = (row >> 4) & 3, rlow = row & 15;
        int kt = k >> 5, kq = (k >> 3) & 3, kk = k & 7;
        size_t idx = (size_t)rg * 16384 + (size_t)((((rt * 8 + kt) * 4 + kq) * 16 + rlow) * 8 + kk);
        ((uint*)(ws + HG_OFF))[idx] =
            ((uint)(unsigned short)hi << 16) | (uint)(unsigned short)lo;
    }
    if (tid < 2048 * SEQ) {                          // x transpose -> [t][row]
        int row = tid / SEQ, tt = tid % SEQ;
        ((float*)(ws + XT_OFF))[tt * 2048 + row] = x[tid];
    }
    if (tid < 1024) {
        ((float*)(ws + BB_OFF))[tid] = b_ih[tid] + b_hh[tid];
        ((float*)(ws + WI_OFF))[tid] = W_ih[tid];
    }
    if (tid < 32) {
        ((uint*)(ws + BAR_OFF))[tid * 64]      = 0;   // step barrier
        ((uint*)(ws + BAR_OFF))[tid * 64 + 16] = 0;   // init barrier
    }
}

// ---------------------------------------------------------------------------
// Step loop, R8: 8-deep frag pipeline (issue x + all 16 loads upfront, per-kt
// counted waits vmcnt(14-2kt); identical constants warm/fc since x is issued
// first/oldest and kt=7 drains to 0). Barrier: pre-add syncthreads kept (adds
// assert all stores drained); tid0 adds; ALL waves poll the agent counter and
// self-release — trailing syncthreads removed. Everything else R7 verbatim.
// ---------------------------------------------------------------------------
template<bool LOC>
__device__ __forceinline__ void run_steps(
    const short* __restrict__ wlo_s, const float* __restrict__ fcw_l,
    float* __restrict__ y_s, const float* __restrict__ xT,
    uint* __restrict__ bar, uint* __restrict__ hg, float* __restrict__ out,
    const bf16x8 (&bhi)[4][8], float (&c)[4],
    const float (&bbg)[4], const float (&wig)[4],
    const float fcb0, const int tid, const int rg, const int s,
    const int lane, const int quad, const int uc, const int rt,
    const int kq_u, const int kk_u)
{
    const int nof = lane & 15;

    for (int t = 0; t <= SEQ; ++t) {
        const uint par = (uint)t & 1u;
        const uint* __restrict__ hsrc = hg + (size_t)par * HG_PAR + (size_t)rg * 16384;
        const uint* fb = hsrc + rt * 4096 + quad * 128 + nof * 8;

        if (t == SEQ) {          // final y only
            if (uc == 0) {
                float p = 0.f;
                uintx4 A[8][2];
                #pragma unroll
                for (int kt = 0; kt < 8; ++kt)
                    frag_issue<LOC>(A[kt][0], A[kt][1], fb + kt * 512);
                #pragma unroll
                for (int kt = 0; kt < 8; ++kt) {
                    uintx4& a0 = A[kt][0];
                    uintx4& a1 = A[kt][1];
                    frag_waitN(14 - 2 * kt, a0, a1);
                    pack16 ph, pl;
                    ph.u[0] = __builtin_amdgcn_perm(a0[1], a0[0], 0x07060302u);
                    ph.u[1] = __builtin_amdgcn_perm(a0[3], a0[2], 0x07060302u);
                    ph.u[2] = __builtin_amdgcn_perm(a1[1], a1[0], 0x07060302u);
                    ph.u[3] = __builtin_amdgcn_perm(a1[3], a1[2], 0x07060302u);
                    pl.u[0] = __builtin_amdgcn_perm(a0[1], a0[0], 0x05040100u);
                    pl.u[1] = __builtin_amdgcn_perm(a0[3], a0[2], 0x05040100u);
                    pl.u[2] = __builtin_amdgcn_perm(a1[1], a1[0], 0x05040100u);
                    pl.u[3] = __builtin_amdgcn_perm(a1[3], a1[2], 0x05040100u);
                    const float* w = fcw_l + kt * 32 + quad * 8;
                    const float4 w0 = *(const float4*)(w);
                    const float4 w1 = *(const float4*)(w + 4);
                    p += w0.x * (bf2f(ph.v[0]) + bf2f(pl.v[0]));
                    p += w0.y * (bf2f(ph.v[1]) + bf2f(pl.v[1]));
                    p += w0.z * (bf2f(ph.v[2]) + bf2f(pl.v[2]));
                    p += w0.w * (bf2f(ph.v[3]) + bf2f(pl.v[3]));
                    p += w1.x * (bf2f(ph.v[4]) + bf2f(pl.v[4]));
                    p += w1.y * (bf2f(ph.v[5]) + bf2f(pl.v[5]));
                    p += w1.z * (bf2f(ph.v[6]) + bf2f(pl.v[6]));
                    p += w1.w * (bf2f(ph.v[7]) + bf2f(pl.v[7]));
                }
                p += __shfl_xor(p, 16);
                p += __shfl_xor(p, 32);
                if (lane < 16) y_s[rt * 16 + lane] = p;
            }
            __syncthreads();
            if (s == 0 && tid < 64)
                out[(rg * 64 + tid) * FLEN + (FLEN - 1)] = y_s[tid] + fcb0;
            break;
        }

        const bool fc = (t >= WARM);
        uintx4 xvv;
        if (!fc)         // x(t): issued FIRST (oldest) so frag counts hold
            asm volatile("global_load_dwordx4 %0, %1, off"
                         : "=v"(xvv)
                         : "v"(xT + t * 2048 + rg * 64 + rt * 16 + quad * 4));

        // ---- 8-deep pipelined frag loads + unpack + MFMA + y-dot ----
        floatx4 acc[4];
        #pragma unroll
        for (int g = 0; g < 4; ++g) acc[g] = (floatx4){0.f, 0.f, 0.f, 0.f};
        float p = 0.f;
        uintx4 A[8][2];
        #pragma unroll
        for (int kt = 0; kt < 8; ++kt)
            frag_issue<LOC>(A[kt][0], A[kt][1], fb + kt * 512);
        #pragma unroll
        for (int kt = 0; kt < 8; ++kt) {
            uintx4& a0 = A[kt][0];
            uintx4& a1 = A[kt][1];
            frag_waitN(14 - 2 * kt, a0, a1);
            pack16 ph, pl;
            ph.u[0] = __builtin_amdgcn_perm(a0[1], a0[0], 0x07060302u);
            ph.u[1] = __builtin_amdgcn_perm(a0[3], a0[2], 0x07060302u);
            ph.u[2] = __builtin_amdgcn_perm(a1[1], a1[0], 0x07060302u);
            ph.u[3] = __builtin_amdgcn_perm(a1[3], a1[2], 0x07060302u);
            pl.u[0] = __builtin_amdgcn_perm(a0[1], a0[0], 0x05040100u);
            pl.u[1] = __builtin_amdgcn_perm(a0[3], a0[2], 0x05040100u);
            pl.u[2] = __builtin_amdgcn_perm(a1[1], a1[0], 0x05040100u);
            pl.u[3] = __builtin_amdgcn_perm(a1[3], a1[2], 0x05040100u);
            if (fc && uc == 0) {
                const float* w = fcw_l + kt * 32 + quad * 8;
                const float4 w0 = *(const float4*)(w);
                const float4 w1 = *(const float4*)(w + 4);
                p += w0.x * (bf2f(ph.v[0]) + bf2f(pl.v[0]));
                p += w0.y * (bf2f(ph.v[1]) + bf2f(pl.v[1]));
                p += w0.z * (bf2f(ph.v[2]) + bf2f(pl.v[2]));
                p += w0.w * (bf2f(ph.v[3]) + bf2f(pl.v[3]));
                p += w1.x * (bf2f(ph.v[4]) + bf2f(pl.v[4]));
                p += w1.y * (bf2f(ph.v[5]) + bf2f(pl.v[5]));
                p += w1.z * (bf2f(ph.v[6]) + bf2f(pl.v[6]));
                p += w1.w * (bf2f(ph.v[7]) + bf2f(pl.v[7]));
            }
            #pragma unroll
            for (int g = 0; g < 4; ++g) {
                bf16x8 bl = *(const bf16x8*)(wlo_s + ((uc * 4 + g) * 8 + kt) * 512 + lane * 8);
                acc[g] = __builtin_amdgcn_mfma_f32_16x16x32_bf16(ph.v, bhi[g][kt], acc[g], 0, 0, 0);
                acc[g] = __builtin_amdgcn_mfma_f32_16x16x32_bf16(pl.v, bhi[g][kt], acc[g], 0, 0, 0);
                acc[g] = __builtin_amdgcn_mfma_f32_16x16x32_bf16(ph.v, bl,        acc[g], 0, 0, 0);
            }
        }

        if (fc) {               // y(t-1) exchange within block (single-writer)
            if (uc == 0) {
                p += __shfl_xor(p, 16);
                p += __shfl_xor(p, 32);
                if (lane < 16) y_s[rt * 16 + lane] = p;
            }
            __syncthreads();
            if (t >= WARM + 1 && s == 0 && tid < 64)
                out[(rg * 64 + tid) * FLEN + (t - (WARM + 1))] = y_s[tid] + fcb0;
        } else {
            // vmcnt is 0 after kt=7's wait; tie xvv so its consumers stay here
            asm volatile("s_waitcnt vmcnt(0)" : "+v"(xvv) :: "memory");
        }

        // ---- elementwise LSTM + h store (verbatim) ----
        uint* __restrict__ hdst = hg + (size_t)(1u - par) * HG_PAR + (size_t)rg * 16384;
        upk4 xcv; xcv.u = xvv;
        const float xin[4] = {xcv.f.x, xcv.f.y, xcv.f.z, xcv.f.w};
        #pragma unroll
        for (int i = 0; i < 4; ++i) {
            const int rlow = quad * 4 + i;
            float inr = fc ? (y_s[rt * 16 + rlow] + fcb0) : xin[i];
            float gi = acc[0][i] + bbg[0] + inr * wig[0];
            float gf = acc[1][i] + bbg[1] + inr * wig[1];
            float gg = acc[2][i] + bbg[2] + inr * wig[2];
            float go = acc[3][i] + bbg[3] + inr * wig[3];
            float cn = fast_sig(gf) * c[i] + fast_sig(gi) * fast_tanh(gg);
            c[i] = cn;
            float h = fast_sig(go) * fast_tanh(cn);
            short hi = f2bf(h);
            short lo = f2bf(h - bf2f(hi));
            const uint hval = ((uint)(unsigned short)hi << 16) | (uint)(unsigned short)lo;
            uint* hp = hdst + ((((rt * 8 + s) * 4 + kq_u) * 16 + rlow) * 8 + kk_u);
            if (LOC)    // write-through L1 -> lands (and stays) in shared L2
                __hip_atomic_store(hp, hval, __ATOMIC_RELAXED, __HIP_MEMORY_SCOPE_WORKGROUP);
            else
                store_llc32(hp, hval);
        }
        asm volatile("s_waitcnt vmcnt(0)" ::: "memory");   // h stores acked
        __syncthreads();        // all threads' stores drained before the add

        // ---- inter-block step barrier: tid0 adds, ALL waves self-release ----
        if (tid == 0)
            __hip_atomic_fetch_add(&bar[rg * 64], 1u, __ATOMIC_RELAXED,
                                   __HIP_MEMORY_SCOPE_AGENT);
        const uint target = 8u * (uint)(t + 1);
        while (__hip_atomic_load(&bar[rg * 64], __ATOMIC_RELAXED,
                                 __HIP_MEMORY_SCOPE_AGENT) < target)
            __builtin_amdgcn_s_sleep(1);
        // no trailing syncthreads: each wave proceeds once the count is seen
    }
}

__global__ void __launch_bounds__(512, 2) lstm_main(
    const float* __restrict__ c0, unsigned char* __restrict__ ws,
    const float* __restrict__ fcw, const float* __restrict__ fcb,
    float* __restrict__ out)
{
    extern __shared__ char smem[];
    short* wlo_s = (short*)smem;                  // 32768 shorts (64 KB)
    float* fcw_l = (float*)(smem + 65536);        // 256 floats (1 KB)
    float* y_s   = (float*)(smem + 66560);        // 64 floats

    const int tid  = threadIdx.x;
    const int blk  = blockIdx.x;
    const int rg   = blk & 31;                    // row-group: 64 rows
    const int s    = blk >> 5;                    // unit-slice: 32 units
    const int wv   = tid >> 6, lane = tid & 63;
    const int quad = lane >> 4, nof = lane & 15;
    const int uc   = wv & 1, rt = wv >> 1;        // wave = (row-tile rt, unit-chunk uc)

    const short* whi_g = (const short*)(ws + WHI_OFF);
    const float* bb    = (const float*)(ws + BB_OFF);
    const float* wi    = (const float*)(ws + WI_OFF);
    const float* xT    = (const float*)(ws + XT_OFF);
    uint* bar          = (uint*)(ws + BAR_OFF);
    uint* hg           = (uint*)(ws + HG_OFF);

    // ---- stage W-lo slice -> LDS (64 KB contiguous) + fcw -> LDS ----
    {
        const uint4* src = (const uint4*)(ws + WLO_OFF) + (size_t)s * 4096;
        uint4* dst = (uint4*)wlo_s;
        for (int i = tid; i < 4096; i += 512) dst[i] = src[i];
        if (tid < 256) fcw_l[tid] = fcw[tid];
    }
    // ---- W-hi fragments -> registers/AGPRs (32 x 16B per lane) ----
    bf16x8 bhi[4][8];
    {
        const bf16x8* src = (const bf16x8*)whi_g;
        #pragma unroll
        for (int g = 0; g < 4; ++g)
            #pragma unroll
            for (int kt = 0; kt < 8; ++kt)
                bhi[g][kt] = src[(size_t)(((s * 2 + uc) * 4 + g) * 8 + kt) * 64 + lane];
    }

    // ---- per-thread constants ----
    const int u = s * 32 + uc * 16 + nof;         // owned hidden unit (elementwise)
    float bbg[4], wig[4];
    #pragma unroll
    for (int g = 0; g < 4; ++g) { bbg[g] = bb[g * 256 + u]; wig[g] = wi[g * 256 + u]; }
    const float fcb0 = fcb[0];
    float c[4];
    #pragma unroll
    for (int i = 0; i < 4; ++i)
        c[i] = c0[(rg * 64 + rt * 16 + quad * 4 + i) * HDIM + u];
    const int kq_u = uc * 2 + (nof >> 3);
    const int kk_u = nof & 7;

    // ---- XCD co-location check: rg-uniform verdict; fallback = LLC ----
    if (tid == 0) {
        store_llc32(&bar[rg * 64 + 32 + s], get_xcc_id() + 1u);
        asm volatile("s_waitcnt vmcnt(0)" ::: "memory");
        __hip_atomic_fetch_add(&bar[rg * 64 + 16], 1u, __ATOMIC_RELAXED,
                               __HIP_MEMORY_SCOPE_AGENT);
        while (__hip_atomic_load(&bar[rg * 64 + 16], __ATOMIC_RELAXED,
                                 __HIP_MEMORY_SCOPE_AGENT) < 8u)
            __builtin_amdgcn_s_sleep(1);
        const uint x0 = load_llc32u(&bar[rg * 64 + 32]);
        int ok = 1;
        #pragma unroll
        for (int j = 1; j < 8; ++j)
            ok &= (load_llc32u(&bar[rg * 64 + 32 + j]) == x0);
        ((int*)y_s)[0] = ok;
    }
    __syncthreads();
    const int l2loc = ((int*)y_s)[0];
    __syncthreads();    // verdict consumed before y_s is reused

    if (l2loc)
        run_steps<true>(wlo_s, fcw_l, y_s, xT, bar, hg, out, bhi, c,
                        bbg, wig, fcb0, tid, rg, s, lane, quad, uc, rt,
                        kq_u, kk_u);
    else
        run_steps<false>(wlo_s, fcw_l, y_s, xT, bar, hg, out, bhi, c,
                         bbg, wig, fcb0, tid, rg, s, lane, quad, uc, rt,
                         kq_u, kk_u);
}

extern "C" void kernel_launch(void* const* d_in, const int* in_sizes, int n_in,
                              void* d_out, int out_size, void* d_ws, size_t ws_size,
                              hipStream_t stream) {
    const float* x    = (const float*)d_in[0];
    const float* h0   = (const float*)d_in[1];
    const float* c0   = (const float*)d_in[2];
    const float* W_ih = (const float*)d_in[3];
    const float* W_hh = (const float*)d_in[4];
    const float* b_ih = (const float*)d_in[5];
    const float* b_hh = (const float*)d_in[6];
    const float* fc_w = (const float*)d_in[7];
    const float* fc_b = (const float*)d_in[8];
    float* out = (float*)d_out;
    unsigned char* ws = (unsigned char*)d_ws;

    lstm_prep<<<2048, 256, 0, stream>>>(W_ih, W_hh, b_ih, b_hh, h0, x, ws);

    static int attr_set = 0;
    if (!attr_set) {
        (void)hipFuncSetAttribute((const void*)lstm_main,
                                  hipFuncAttributeMaxDynamicSharedMemorySize, LDS_BYTES);
        attr_set = 1;
    }
    void* args[] = {(void*)&c0, (void*)&ws, (void*)&fc_w, (void*)&fc_b, (void*)&out};
    (void)hipLaunchCooperativeKernel((const void*)lstm_main, dim3(256), dim3(512),
                                     args, LDS_BYTES, stream);
}

// Round 9
// 617.282 us; speedup vs baseline: 1.2070x; 1.2070x over previous
//
#include <hip/hip_runtime.h>

#define SEQ   120
#define WARM  96
#define FLEN  24
#define HDIM  256

typedef __attribute__((ext_vector_type(8))) short bf16x8;
typedef __attribute__((ext_vector_type(4))) float floatx4;
typedef __attribute__((ext_vector_type(4))) unsigned int uintx4;
typedef unsigned int uint;
typedef unsigned long long ull;

// ws layout (bytes):
//   WHI  [0, 512K)        bf16 frag-linear W-hi
//   WLO  [512K, 1M)       bf16 frag-linear W-lo
//   BB   [1M, +4K)        f32 b_ih+b_hh
//   WI   [1M+4K, +4K)     f32 W_ih col
//   BAR  [1M+8K, +8K)     uint bar[32], stride 64 uints (256 B)
//                         +0: step barrier, +16: init barrier, +32..39: xcc ids
//   HG   [1M+16K, +4M)    uint h packed (hi<<16|lo), 2 parities x 32 rg x 16384
//                         frag-linear: idx = (((rt*8+kt)*4+kq)*16+rlow)*8+kk
//   XT   [5M+16K, +960K)  f32 x transposed [t][row]
#define WHI_OFF 0
#define WLO_OFF (512 * 1024)
#define BB_OFF  (1024 * 1024)
#define WI_OFF  (1024 * 1024 + 4096)
#define BAR_OFF (1024 * 1024 + 8192)
#define HG_OFF  (1024 * 1024 + 16384)
#define HG_PAR  524288              // uints per parity
#define XT_OFF  (HG_OFF + 4 * 1024 * 1024)

#define LDS_BYTES 66816             // wlo 64K | fcw 1K | y 256B

__device__ __forceinline__ short f2bf(float v) {
    unsigned u = __float_as_uint(v);
    u += 0x7FFF + ((u >> 16) & 1);              // RNE
    return (short)(u >> 16);
}
__device__ __forceinline__ float bf2f(short s) {
    return __uint_as_float(((unsigned)(unsigned short)s) << 16);
}
__device__ __forceinline__ float fast_rcp(float x) {
    return __builtin_amdgcn_rcpf(x);
}
__device__ __forceinline__ float fast_sig(float x) {
    return fast_rcp(1.0f + __expf(-x));
}
__device__ __forceinline__ float fast_tanh(float x) {
    return 1.0f - 2.0f * fast_rcp(__expf(2.0f * x) + 1.0f);
}

// ---- LLC-coherent (cross-XCD) helpers: agent scope -> device SC bits ----
__device__ __forceinline__ uint load_llc32u(const uint* p) {
    return __hip_atomic_load(p, __ATOMIC_RELAXED, __HIP_MEMORY_SCOPE_AGENT);
}
__device__ __forceinline__ void store_llc32(uint* p, uint v) {
    __hip_atomic_store(p, v, __ATOMIC_RELAXED, __HIP_MEMORY_SCOPE_AGENT);
}

// XCC (XCD) id of the CU executing this wave [measured: learn_hip m09]
__device__ __forceinline__ uint get_xcc_id() {
    uint x;
    asm volatile("s_getreg_b32 %0, hwreg(HW_REG_XCC_ID)" : "=s"(x));
    return x;
}

// ---- direct frag-load pipeline primitives ----
// LOC: sc0 (bypass stale L1, served by shared L2).  !LOC: sc0 sc1 (LLC).
template<bool LOC>
__device__ __forceinline__ void frag_issue(uintx4& d0, uintx4& d1, const uint* p) {
    if constexpr (LOC) {
        asm volatile("global_load_dwordx4 %0, %1, off sc0" : "=v"(d0) : "v"(p));
        asm volatile("global_load_dwordx4 %0, %1, off sc0" : "=v"(d1) : "v"(p + 4));
    } else {
        asm volatile("global_load_dwordx4 %0, %1, off sc0 sc1" : "=v"(d0) : "v"(p));
        asm volatile("global_load_dwordx4 %0, %1, off sc0 sc1" : "=v"(d1) : "v"(p + 4));
    }
}
// counted wait, dataflow-tied to the consumed pair ("+v": consumers cannot be
// hoisted past the wait — rule-18 fix pattern). vmcnt decrements in issue
// order; the kt region contains no compiler VMEM, so the counts are exact.
// n is constant after full unroll -> switch folds to a single s_waitcnt.
__device__ __forceinline__ void frag_waitN(int n, uintx4& d0, uintx4& d1) {
    switch (n) {
    case 14: asm volatile("s_waitcnt vmcnt(14)" : "+v"(d0), "+v"(d1) :: "memory"); break;
    case 12: asm volatile("s_waitcnt vmcnt(12)" : "+v"(d0), "+v"(d1) :: "memory"); break;
    case 10: asm volatile("s_waitcnt vmcnt(10)" : "+v"(d0), "+v"(d1) :: "memory"); break;
    case 8:  asm volatile("s_waitcnt vmcnt(8)"  : "+v"(d0), "+v"(d1) :: "memory"); break;
    case 6:  asm volatile("s_waitcnt vmcnt(6)"  : "+v"(d0), "+v"(d1) :: "memory"); break;
    case 4:  asm volatile("s_waitcnt vmcnt(4)"  : "+v"(d0), "+v"(d1) :: "memory"); break;
    case 2:  asm volatile("s_waitcnt vmcnt(2)"  : "+v"(d0), "+v"(d1) :: "memory"); break;
    default: asm volatile("s_waitcnt vmcnt(0)"  : "+v"(d0), "+v"(d1) :: "memory"); break;
    }
}

union pack16 { uint u[4]; bf16x8 v; };
union upk4   { uintx4 u; float4 f; };

__global__ __launch_bounds__(256) void lstm_prep(
    const float* __restrict__ W_ih, const float* __restrict__ W_hh,
    const float* __restrict__ b_ih, const float* __restrict__ b_hh,
    const float* __restrict__ h0, const float* __restrict__ x,
    unsigned char* __restrict__ ws)
{
    int tid = blockIdx.x * 256 + threadIdx.x;       // grid 2048*256 = 524288
    if (tid < 262144) {
        int col = tid >> 8, k = tid & 255;          // col = gate*256+unit
        float v  = W_hh[tid];
        short hi = f2bf(v);
        short lo = f2bf(v - bf2f(hi));
        int g = col >> 8, rem = col & 255;
        int s = rem >> 5, uo = rem & 31, uc = uo >> 4, n = uo & 15;
        int kt = k >> 5, kq = (k >> 3) & 3, j = k & 7;
        size_t unit = ((((size_t)(s * 2 + uc) * 4 + g) * 8 + kt) * 64 + kq * 16 + n);
        ((short*)(ws + WHI_OFF))[unit * 8 + j] = hi;
        ((short*)(ws + WLO_OFF))[unit * 8 + j] = lo;
    }
    if (tid < 524288) {                              // pack h0 -> parity 0
        int row = tid >> 8, k = tid & 255;
        float v  = h0[tid];
        short hi = f2bf(v);
        short lo = f2bf(v - bf2f(hi));
        int rg = row >> 6, rt = (row >> 4) & 3, rlow = row & 15;
        int kt = k >> 5, kq = (k >> 3) & 3, kk = k & 7;
        size_t idx = (size_t)rg * 16384 + (size_t)((((rt * 8 + kt) * 4 + kq) * 16 + rlow) * 8 + kk);
        ((uint*)(ws + HG_OFF))[idx] =
            ((uint)(unsigned short)hi << 16) | (uint)(unsigned short)lo;
    }
    if (tid < 2048 * SEQ) {                          // x transpose -> [t][row]
        int row = tid / SEQ, tt = tid % SEQ;
        ((float*)(ws + XT_OFF))[tt * 2048 + row] = x[tid];
    }
    if (tid < 1024) {
        ((float*)(ws + BB_OFF))[tid] = b_ih[tid] + b_hh[tid];
        ((float*)(ws + WI_OFF))[tid] = W_ih[tid];
    }
    if (tid < 32) {
        ((uint*)(ws + BAR_OFF))[tid * 64]      = 0;   // step barrier
        ((uint*)(ws + BAR_OFF))[tid * 64 + 16] = 0;   // init barrier
    }
}

// ---------------------------------------------------------------------------
// Step loop, R9 = R7 + 8-deep frag pipeline ONLY (strict bisect of R8).
// Issue x (warm; first/oldest) + all 16 frag loads upfront; per-kt counted
// waits vmcnt(14-2kt) — constants identical warm/fc; kt=7 drains to 0 (covers
// x). Barrier: R7-verbatim (tid0 add, tid0 poll, trailing syncthreads).
// t==SEQ path, elementwise, stores: R7 verbatim.
// ---------------------------------------------------------------------------
template<bool LOC>
__device__ __forceinline__ void run_steps(
    const short* __restrict__ wlo_s, const float* __restrict__ fcw_l,
    float* __restrict__ y_s, const float* __restrict__ xT,
    uint* __restrict__ bar, uint* __restrict__ hg, float* __restrict__ out,
    const bf16x8 (&bhi)[4][8], float (&c)[4],
    const float (&bbg)[4], const float (&wig)[4],
    const float fcb0, const int tid, const int rg, const int s,
    const int lane, const int quad, const int uc, const int rt,
    const int kq_u, const int kk_u)
{
    const int nof = lane & 15;

    for (int t = 0; t <= SEQ; ++t) {
        const uint par = (uint)t & 1u;
        const uint* __restrict__ hsrc = hg + (size_t)par * HG_PAR + (size_t)rg * 16384;
        const uint* fb = hsrc + rt * 4096 + quad * 128 + nof * 8;

        if (t == SEQ) {          // final y only (R7 verbatim)
            if (uc == 0) {
                float p = 0.f;
                #pragma unroll
                for (int kt = 0; kt < 8; ++kt) {
                    uintx4 a0, a1;
                    frag_issue<LOC>(a0, a1, fb + kt * 512);
                    frag_waitN(0, a0, a1);
                    pack16 ph, pl;
                    ph.u[0] = __builtin_amdgcn_perm(a0[1], a0[0], 0x07060302u);
                    ph.u[1] = __builtin_amdgcn_perm(a0[3], a0[2], 0x07060302u);
                    ph.u[2] = __builtin_amdgcn_perm(a1[1], a1[0], 0x07060302u);
                    ph.u[3] = __builtin_amdgcn_perm(a1[3], a1[2], 0x07060302u);
                    pl.u[0] = __builtin_amdgcn_perm(a0[1], a0[0], 0x05040100u);
                    pl.u[1] = __builtin_amdgcn_perm(a0[3], a0[2], 0x05040100u);
                    pl.u[2] = __builtin_amdgcn_perm(a1[1], a1[0], 0x05040100u);
                    pl.u[3] = __builtin_amdgcn_perm(a1[3], a1[2], 0x05040100u);
                    const float* w = fcw_l + kt * 32 + quad * 8;
                    const float4 w0 = *(const float4*)(w);
                    const float4 w1 = *(const float4*)(w + 4);
                    p += w0.x * (bf2f(ph.v[0]) + bf2f(pl.v[0]));
                    p += w0.y * (bf2f(ph.v[1]) + bf2f(pl.v[1]));
                    p += w0.z * (bf2f(ph.v[2]) + bf2f(pl.v[2]));
                    p += w0.w * (bf2f(ph.v[3]) + bf2f(pl.v[3]));
                    p += w1.x * (bf2f(ph.v[4]) + bf2f(pl.v[4]));
                    p += w1.y * (bf2f(ph.v[5]) + bf2f(pl.v[5]));
                    p += w1.z * (bf2f(ph.v[6]) + bf2f(pl.v[6]));
                    p += w1.w * (bf2f(ph.v[7]) + bf2f(pl.v[7]));
                }
                p += __shfl_xor(p, 16);
                p += __shfl_xor(p, 32);
                if (lane < 16) y_s[rt * 16 + lane] = p;
            }
            __syncthreads();
            if (s == 0 && tid < 64)
                out[(rg * 64 + tid) * FLEN + (FLEN - 1)] = y_s[tid] + fcb0;
            break;
        }

        const bool fc = (t >= WARM);
        uintx4 xvv;
        if (!fc)         // x(t): issued FIRST (oldest) so frag counts hold
            asm volatile("global_load_dwordx4 %0, %1, off"
                         : "=v"(xvv)
                         : "v"(xT + t * 2048 + rg * 64 + rt * 16 + quad * 4));

        // ---- 8-deep pipelined frag loads + unpack + MFMA + y-dot ----
        floatx4 acc[4];
        #pragma unroll
        for (int g = 0; g < 4; ++g) acc[g] = (floatx4){0.f, 0.f, 0.f, 0.f};
        float p = 0.f;
        uintx4 A[8][2];
        #pragma unroll
        for (int kt = 0; kt < 8; ++kt)
            frag_issue<LOC>(A[kt][0], A[kt][1], fb + kt * 512);
        #pragma unroll
        for (int kt = 0; kt < 8; ++kt) {
            uintx4& a0 = A[kt][0];
            uintx4& a1 = A[kt][1];
            frag_waitN(14 - 2 * kt, a0, a1);
            pack16 ph, pl;
            ph.u[0] = __builtin_amdgcn_perm(a0[1], a0[0], 0x07060302u);
            ph.u[1] = __builtin_amdgcn_perm(a0[3], a0[2], 0x07060302u);
            ph.u[2] = __builtin_amdgcn_perm(a1[1], a1[0], 0x07060302u);
            ph.u[3] = __builtin_amdgcn_perm(a1[3], a1[2], 0x07060302u);
            pl.u[0] = __builtin_amdgcn_perm(a0[1], a0[0], 0x05040100u);
            pl.u[1] = __builtin_amdgcn_perm(a0[3], a0[2], 0x05040100u);
            pl.u[2] = __builtin_amdgcn_perm(a1[1], a1[0], 0x05040100u);
            pl.u[3] = __builtin_amdgcn_perm(a1[3], a1[2], 0x05040100u);
            if (fc && uc == 0) {
                const float* w = fcw_l + kt * 32 + quad * 8;
                const float4 w0 = *(const float4*)(w);
                const float4 w1 = *(const float4*)(w + 4);
                p += w0.x * (bf2f(ph.v[0]) + bf2f(pl.v[0]));
                p += w0.y * (bf2f(ph.v[1]) + bf2f(pl.v[1]));
                p += w0.z * (bf2f(ph.v[2]) + bf2f(pl.v[2]));
                p += w0.w * (bf2f(ph.v[3]) + bf2f(pl.v[3]));
                p += w1.x * (bf2f(ph.v[4]) + bf2f(pl.v[4]));
                p += w1.y * (bf2f(ph.v[5]) + bf2f(pl.v[5]));
                p += w1.z * (bf2f(ph.v[6]) + bf2f(pl.v[6]));
                p += w1.w * (bf2f(ph.v[7]) + bf2f(pl.v[7]));
            }
            #pragma unroll
            for (int g = 0; g < 4; ++g) {
                bf16x8 bl = *(const bf16x8*)(wlo_s + ((uc * 4 + g) * 8 + kt) * 512 + lane * 8);
                acc[g] = __builtin_amdgcn_mfma_f32_16x16x32_bf16(ph.v, bhi[g][kt], acc[g], 0, 0, 0);
                acc[g] = __builtin_amdgcn_mfma_f32_16x16x32_bf16(pl.v, bhi[g][kt], acc[g], 0, 0, 0);
                acc[g] = __builtin_amdgcn_mfma_f32_16x16x32_bf16(ph.v, bl,        acc[g], 0, 0, 0);
            }
        }

        if (fc) {               // y(t-1) exchange within block (single-writer)
            if (uc == 0) {
                p += __shfl_xor(p, 16);
                p += __shfl_xor(p, 32);
                if (lane < 16) y_s[rt * 16 + lane] = p;
            }
            __syncthreads();
            if (t >= WARM + 1 && s == 0 && tid < 64)
                out[(rg * 64 + tid) * FLEN + (t - (WARM + 1))] = y_s[tid] + fcb0;
        } else {
            // vmcnt is 0 after kt=7's wait; tie xvv so its consumers stay here
            asm volatile("s_waitcnt vmcnt(0)" : "+v"(xvv) :: "memory");
        }

        // ---- elementwise LSTM + h store (R7 verbatim) ----
        uint* __restrict__ hdst = hg + (size_t)(1u - par) * HG_PAR + (size_t)rg * 16384;
        upk4 xcv; xcv.u = xvv;
        const float xin[4] = {xcv.f.x, xcv.f.y, xcv.f.z, xcv.f.w};
        #pragma unroll
        for (int i = 0; i < 4; ++i) {
            const int rlow = quad * 4 + i;
            float inr = fc ? (y_s[rt * 16 + rlow] + fcb0) : xin[i];
            float gi = acc[0][i] + bbg[0] + inr * wig[0];
            float gf = acc[1][i] + bbg[1] + inr * wig[1];
            float gg = acc[2][i] + bbg[2] + inr * wig[2];
            float go = acc[3][i] + bbg[3] + inr * wig[3];
            float cn = fast_sig(gf) * c[i] + fast_sig(gi) * fast_tanh(gg);
            c[i] = cn;
            float h = fast_sig(go) * fast_tanh(cn);
            short hi = f2bf(h);
            short lo = f2bf(h - bf2f(hi));
            const uint hval = ((uint)(unsigned short)hi << 16) | (uint)(unsigned short)lo;
            uint* hp = hdst + ((((rt * 8 + s) * 4 + kq_u) * 16 + rlow) * 8 + kk_u);
            if (LOC)    // write-through L1 -> lands (and stays) in shared L2
                __hip_atomic_store(hp, hval, __ATOMIC_RELAXED, __HIP_MEMORY_SCOPE_WORKGROUP);
            else
                store_llc32(hp, hval);
        }
        asm volatile("s_waitcnt vmcnt(0)" ::: "memory");   // h stores acked
        __syncthreads();                                    // whole block done

        // ---- inter-block step barrier: R7-verbatim agent-scope LLC path ----
        if (tid == 0) {
            __hip_atomic_fetch_add(&bar[rg * 64], 1u, __ATOMIC_RELAXED,
                                   __HIP_MEMORY_SCOPE_AGENT);
            const uint target = 8u * (uint)(t + 1);
            while (__hip_atomic_load(&bar[rg * 64], __ATOMIC_RELAXED,
                                     __HIP_MEMORY_SCOPE_AGENT) < target)
                __builtin_amdgcn_s_sleep(1);
        }
        __syncthreads();
    }
}

__global__ void __launch_bounds__(512, 2) lstm_main(
    const float* __restrict__ c0, unsigned char* __restrict__ ws,
    const float* __restrict__ fcw, const float* __restrict__ fcb,
    float* __restrict__ out)
{
    extern __shared__ char smem[];
    short* wlo_s = (short*)smem;                  // 32768 shorts (64 KB)
    float* fcw_l = (float*)(smem + 65536);        // 256 floats (1 KB)
    float* y_s   = (float*)(smem + 66560);        // 64 floats

    const int tid  = threadIdx.x;
    const int blk  = blockIdx.x;
    const int rg   = blk & 31;                    // row-group: 64 rows
    const int s    = blk >> 5;                    // unit-slice: 32 units
    const int wv   = tid >> 6, lane = tid & 63;
    const int quad = lane >> 4, nof = lane & 15;
    const int uc   = wv & 1, rt = wv >> 1;        // wave = (row-tile rt, unit-chunk uc)

    const short* whi_g = (const short*)(ws + WHI_OFF);
    const float* bb    = (const float*)(ws + BB_OFF);
    const float* wi    = (const float*)(ws + WI_OFF);
    const float* xT    = (const float*)(ws + XT_OFF);
    uint* bar          = (uint*)(ws + BAR_OFF);
    uint* hg           = (uint*)(ws + HG_OFF);

    // ---- stage W-lo slice -> LDS (64 KB contiguous) + fcw -> LDS ----
    {
        const uint4* src = (const uint4*)(ws + WLO_OFF) + (size_t)s * 4096;
        uint4* dst = (uint4*)wlo_s;
        for (int i = tid; i < 4096; i += 512) dst[i] = src[i];
        if (tid < 256) fcw_l[tid] = fcw[tid];
    }
    // ---- W-hi fragments -> registers/AGPRs (32 x 16B per lane) ----
    bf16x8 bhi[4][8];
    {
        const bf16x8* src = (const bf16x8*)whi_g;
        #pragma unroll
        for (int g = 0; g < 4; ++g)
            #pragma unroll
            for (int kt = 0; kt < 8; ++kt)
                bhi[g][kt] = src[(size_t)(((s * 2 + uc) * 4 + g) * 8 + kt) * 64 + lane];
    }

    // ---- per-thread constants ----
    const int u = s * 32 + uc * 16 + nof;         // owned hidden unit (elementwise)
    float bbg[4], wig[4];
    #pragma unroll
    for (int g = 0; g < 4; ++g) { bbg[g] = bb[g * 256 + u]; wig[g] = wi[g * 256 + u]; }
    const float fcb0 = fcb[0];
    float c[4];
    #pragma unroll
    for (int i = 0; i < 4; ++i)
        c[i] = c0[(rg * 64 + rt * 16 + quad * 4 + i) * HDIM + u];
    const int kq_u = uc * 2 + (nof >> 3);
    const int kk_u = nof & 7;

    // ---- XCD co-location check: rg-uniform verdict; fallback = LLC ----
    if (tid == 0) {
        store_llc32(&bar[rg * 64 + 32 + s], get_xcc_id() + 1u);
        asm volatile("s_waitcnt vmcnt(0)" ::: "memory");
        __hip_atomic_fetch_add(&bar[rg * 64 + 16], 1u, __ATOMIC_RELAXED,
                               __HIP_MEMORY_SCOPE_AGENT);
        while (__hip_atomic_load(&bar[rg * 64 + 16], __ATOMIC_RELAXED,
                                 __HIP_MEMORY_SCOPE_AGENT) < 8u)
            __builtin_amdgcn_s_sleep(1);
        const uint x0 = load_llc32u(&bar[rg * 64 + 32]);
        int ok = 1;
        #pragma unroll
        for (int j = 1; j < 8; ++j)
            ok &= (load_llc32u(&bar[rg * 64 + 32 + j]) == x0);
        ((int*)y_s)[0] = ok;
    }
    __syncthreads();
    const int l2loc = ((int*)y_s)[0];
    __syncthreads();    // verdict consumed before y_s is reused

    if (l2loc)
        run_steps<true>(wlo_s, fcw_l, y_s, xT, bar, hg, out, bhi, c,
                        bbg, wig, fcb0, tid, rg, s, lane, quad, uc, rt,
                        kq_u, kk_u);
    else
        run_steps<false>(wlo_s, fcw_l, y_s, xT, bar, hg, out, bhi, c,
                         bbg, wig, fcb0, tid, rg, s, lane, quad, uc, rt,
                         kq_u, kk_u);
}

extern "C" void kernel_launch(void* const* d_in, const int* in_sizes, int n_in,
                              void* d_out, int out_size, void* d_ws, size_t ws_size,
                              hipStream_t stream) {
    const float* x    = (const float*)d_in[0];
    const float* h0   = (const float*)d_in[1];
    const float* c0   = (const float*)d_in[2];
    const float* W_ih = (const float*)d_in[3];
    const float* W_hh = (const float*)d_in[4];
    const float* b_ih = (const float*)d_in[5];
    const float* b_hh = (const float*)d_in[6];
    const float* fc_w = (const float*)d_in[7];
    const float* fc_b = (const float*)d_in[8];
    float* out = (float*)d_out;
    unsigned char* ws = (unsigned char*)d_ws;

    lstm_prep<<<2048, 256, 0, stream>>>(W_ih, W_hh, b_ih, b_hh, h0, x, ws);

    static int attr_set = 0;
    if (!attr_set) {
        (void)hipFuncSetAttribute((const void*)lstm_main,
                                  hipFuncAttributeMaxDynamicSharedMemorySize, LDS_BYTES);
        attr_set = 1;
    }
    void* args[] = {(void*)&c0, (void*)&ws, (void*)&fc_w, (void*)&fc_b, (void*)&out};
    (void)hipLaunchCooperativeKernel((const void*)lstm_main, dim3(256), dim3(512),
                                     args, LDS_BYTES, stream);
}

// Round 11
// 542.753 us; speedup vs baseline: 1.3727x; 1.1373x over previous
//
#include <hip/hip_runtime.h>

#define SEQ   120
#define WARM  96
#define FLEN  24
#define HDIM  256

typedef __attribute__((ext_vector_type(8))) short bf16x8;
typedef __attribute__((ext_vector_type(4))) float floatx4;
typedef __attribute__((ext_vector_type(4))) unsigned int uintx4;
typedef unsigned int uint;
typedef unsigned long long ull;

// ws layout (bytes):
//   WHI  [0, 512K)        bf16 frag-linear W-hi
//   WLO  [512K, 1M)       bf16 frag-linear W-lo
//   BB   [1M, +4K)        f32 b_ih+b_hh
//   WI   [1M+4K, +4K)     f32 W_ih col
//   BAR  [1M+8K, +8K)     uint bar[32], stride 64 uints (256 B)
//                         +0: step barrier, +16: init barrier, +32..39: xcc ids
//   HG   [1M+16K, +4M)    uint h packed (hi<<16|lo), 2 parities x 32 rg x 16384
//                         frag-linear: idx = (((rt*8+kt)*4+kq)*16+rlow)*8+kk
//   XT   [5M+16K, +960K)  f32 x transposed [t][row]
#define WHI_OFF 0
#define WLO_OFF (512 * 1024)
#define BB_OFF  (1024 * 1024)
#define WI_OFF  (1024 * 1024 + 4096)
#define BAR_OFF (1024 * 1024 + 8192)
#define HG_OFF  (1024 * 1024 + 16384)
#define HG_PAR  524288              // uints per parity
#define XT_OFF  (HG_OFF + 4 * 1024 * 1024)

#define LDS_BYTES 66816             // wlo 64K | fcw 1K | y 256B

__device__ __forceinline__ short f2bf(float v) {
    unsigned u = __float_as_uint(v);
    u += 0x7FFF + ((u >> 16) & 1);              // RNE
    return (short)(u >> 16);
}
__device__ __forceinline__ float bf2f(short s) {
    return __uint_as_float(((unsigned)(unsigned short)s) << 16);
}
__device__ __forceinline__ float fast_rcp(float x) {
    return __builtin_amdgcn_rcpf(x);
}
__device__ __forceinline__ float fast_sig(float x) {
    return fast_rcp(1.0f + __expf(-x));
}
__device__ __forceinline__ float fast_tanh(float x) {
    return 1.0f - 2.0f * fast_rcp(__expf(2.0f * x) + 1.0f);
}

// ---- LLC-coherent (cross-XCD) helpers: agent scope -> device SC bits ----
__device__ __forceinline__ uint load_llc32u(const uint* p) {
    return __hip_atomic_load(p, __ATOMIC_RELAXED, __HIP_MEMORY_SCOPE_AGENT);
}
__device__ __forceinline__ void store_llc32(uint* p, uint v) {
    __hip_atomic_store(p, v, __ATOMIC_RELAXED, __HIP_MEMORY_SCOPE_AGENT);
}

// XCC (XCD) id of the CU executing this wave [measured: learn_hip m09]
__device__ __forceinline__ uint get_xcc_id() {
    uint x;
    asm volatile("s_getreg_b32 %0, hwreg(HW_REG_XCC_ID)" : "=s"(x));
    return x;
}

// ---- direct frag-load pipeline primitives (R7-proven, 2-deep) ----
// LOC: PLAIN loads (L1-cacheable) — coherence restored by a per-step
//      buffer_inv (L1-only invalidate) executed after the barrier release,
//      before any frag load. L1 refills then come from the shared XCD L2,
//      which producers wrote through (vmcnt-acked) before their barrier add.
//      The uc-pair waves of each rt read IDENTICAL frags -> second reader
//      hits L1 / MSHR-merges, halving L2-side h traffic.
// !LOC: sc0 sc1 (LLC), R7 verbatim.
template<bool LOC>
__device__ __forceinline__ void frag_issue(uintx4& d0, uintx4& d1, const uint* p) {
    if constexpr (LOC) {
        asm volatile("global_load_dwordx4 %0, %1, off" : "=v"(d0) : "v"(p));
        asm volatile("global_load_dwordx4 %0, %1, off" : "=v"(d1) : "v"(p + 4));
    } else {
        asm volatile("global_load_dwordx4 %0, %1, off sc0 sc1" : "=v"(d0) : "v"(p));
        asm volatile("global_load_dwordx4 %0, %1, off sc0 sc1" : "=v"(d1) : "v"(p + 4));
    }
}
// counted waits, dataflow-tied to the consumed pair ("+v": consumers cannot
// be hoisted past the wait — rule-18 fix pattern). vmcnt decrements in issue
// order; the kt region contains no compiler VMEM, so the counts are exact.
__device__ __forceinline__ void frag_wait2(uintx4& d0, uintx4& d1) {
    asm volatile("s_waitcnt vmcnt(2)" : "+v"(d0), "+v"(d1) :: "memory");
}
__device__ __forceinline__ void frag_wait0(uintx4& d0, uintx4& d1) {
    asm volatile("s_waitcnt vmcnt(0)" : "+v"(d0), "+v"(d1) :: "memory");
}

union pack16 { uint u[4]; bf16x8 v; };
union upk4   { uintx4 u; float4 f; };

__global__ __launch_bounds__(256) void lstm_prep(
    const float* __restrict__ W_ih, const float* __restrict__ W_hh,
    const float* __restrict__ b_ih, const float* __restrict__ b_hh,
    const float* __restrict__ h0, const float* __restrict__ x,
    unsigned char* __restrict__ ws)
{
    int tid = blockIdx.x * 256 + threadIdx.x;       // grid 2048*256 = 524288
    if (tid < 262144) {
        int col = tid >> 8, k = tid & 255;          // col = gate*256+unit
        float v  = W_hh[tid];
        short hi = f2bf(v);
        short lo = f2bf(v - bf2f(hi));
        int g = col >> 8, rem = col & 255;
        int s = rem >> 5, uo = rem & 31, uc = uo >> 4, n = uo & 15;
        int kt = k >> 5, kq = (k >> 3) & 3, j = k & 7;
        size_t unit = ((((size_t)(s * 2 + uc) * 4 + g) * 8 + kt) * 64 + kq * 16 + n);
        ((short*)(ws + WHI_OFF))[unit * 8 + j] = hi;
        ((short*)(ws + WLO_OFF))[unit * 8 + j] = lo;
    }
    if (tid < 524288) {                              // pack h0 -> parity 0
        int row = tid >> 8, k = tid & 255;
        float v  = h0[tid];
        short hi = f2bf(v);
        short lo = f2bf(v - bf2f(hi));
        int rg = row >> 6, rt = (row >> 4) & 3, rlow = row & 15;
        int kt = k >> 5, kq = (k >> 3) & 3, kk = k & 7;
        size_t idx = (size_t)rg * 16384 + (size_t)((((rt * 8 + kt) * 4 + kq) * 16 + rlow) * 8 + kk);
        ((uint*)(ws + HG_OFF))[idx] =
            ((uint)(unsigned short)hi << 16) | (uint)(unsigned short)lo;
    }
    if (tid < 2048 * SEQ) {                          // x transpose -> [t][row]
        int row = tid / SEQ, tt = tid % SEQ;
        ((float*)(ws + XT_OFF))[tt * 2048 + row] = x[tid];
    }
    if (tid < 1024) {
        ((float*)(ws + BB_OFF))[tid] = b_ih[tid] + b_hh[tid];
        ((float*)(ws + WI_OFF))[tid] = W_ih[tid];
    }
    if (tid < 32) {
        ((uint*)(ws + BAR_OFF))[tid * 64]      = 0;   // step barrier
        ((uint*)(ws + BAR_OFF))[tid * 64 + 16] = 0;   // init barrier
    }
}

// ---------------------------------------------------------------------------
// Step loop, R11 = R7-verbatim except the LOC frag-load path:
//   plain (L1-cacheable) loads + one buffer_inv (L1-only invalidate, the
//   gfx940+ instruction LLVM emits for agent-acquire) per wave per step,
//   placed after the barrier release and before any frag load. Staleness
//   window (L1 lines cached at t-2, overwritten by producer CUs at t-1) is
//   closed by the inv; refills come from the shared L2 which producers
//   wrote through before their barrier add. Barrier: R7-verbatim agent-scope
//   LLC path (L2-local barrier retired after 3 container-level strikes).
// ---------------------------------------------------------------------------
template<bool LOC>
__device__ __forceinline__ void run_steps(
    const short* __restrict__ wlo_s, const float* __restrict__ fcw_l,
    float* __restrict__ y_s, const float* __restrict__ xT,
    uint* __restrict__ bar, uint* __restrict__ hg, float* __restrict__ out,
    const bf16x8 (&bhi)[4][8], float (&c)[4],
    const float (&bbg)[4], const float (&wig)[4],
    const float fcb0, const int tid, const int rg, const int s,
    const int lane, const int quad, const int uc, const int rt,
    const int kq_u, const int kk_u)
{
    const int nof = lane & 15;

    for (int t = 0; t <= SEQ; ++t) {
        const uint par = (uint)t & 1u;
        const uint* __restrict__ hsrc = hg + (size_t)par * HG_PAR + (size_t)rg * 16384;
        const uint* fb = hsrc + rt * 4096 + quad * 128 + nof * 8;

        // ---- L1 invalidate: drop lines cached at t-2 (producers rewrote
        //      them at t-1). L1-only; the shared L2 (fresh data) is untouched.
        if constexpr (LOC)
            asm volatile("buffer_inv" ::: "memory");

        if (t == SEQ) {          // final y only (R7 verbatim)
            if (uc == 0) {
                float p = 0.f;
                #pragma unroll
                for (int kt = 0; kt < 8; ++kt) {
                    uintx4 a0, a1;
                    frag_issue<LOC>(a0, a1, fb + kt * 512);
                    frag_wait0(a0, a1);
                    pack16 ph, pl;
                    ph.u[0] = __builtin_amdgcn_perm(a0[1], a0[0], 0x07060302u);
                    ph.u[1] = __builtin_amdgcn_perm(a0[3], a0[2], 0x07060302u);
                    ph.u[2] = __builtin_amdgcn_perm(a1[1], a1[0], 0x07060302u);
                    ph.u[3] = __builtin_amdgcn_perm(a1[3], a1[2], 0x07060302u);
                    pl.u[0] = __builtin_amdgcn_perm(a0[1], a0[0], 0x05040100u);
                    pl.u[1] = __builtin_amdgcn_perm(a0[3], a0[2], 0x05040100u);
                    pl.u[2] = __builtin_amdgcn_perm(a1[1], a1[0], 0x05040100u);
                    pl.u[3] = __builtin_amdgcn_perm(a1[3], a1[2], 0x05040100u);
                    const float* w = fcw_l + kt * 32 + quad * 8;
                    const float4 w0 = *(const float4*)(w);
                    const float4 w1 = *(const float4*)(w + 4);
                    p += w0.x * (bf2f(ph.v[0]) + bf2f(pl.v[0]));
                    p += w0.y * (bf2f(ph.v[1]) + bf2f(pl.v[1]));
                    p += w0.z * (bf2f(ph.v[2]) + bf2f(pl.v[2]));
                    p += w0.w * (bf2f(ph.v[3]) + bf2f(pl.v[3]));
                    p += w1.x * (bf2f(ph.v[4]) + bf2f(pl.v[4]));
                    p += w1.y * (bf2f(ph.v[5]) + bf2f(pl.v[5]));
                    p += w1.z * (bf2f(ph.v[6]) + bf2f(pl.v[6]));
                    p += w1.w * (bf2f(ph.v[7]) + bf2f(pl.v[7]));
                }
                p += __shfl_xor(p, 16);
                p += __shfl_xor(p, 32);
                if (lane < 16) y_s[rt * 16 + lane] = p;
            }
            __syncthreads();
            if (s == 0 && tid < 64)
                out[(rg * 64 + tid) * FLEN + (FLEN - 1)] = y_s[tid] + fcb0;
            break;
        }

        const bool fc = (t >= WARM);
        uintx4 xvv;
        if (!fc)         // x(t): own asm load so vmcnt counting stays exact
            asm volatile("global_load_dwordx4 %0, %1, off"
                         : "=v"(xvv)
                         : "v"(xT + t * 2048 + rg * 64 + rt * 16 + quad * 4));

        // ---- 2-deep pipelined frag loads + unpack + MFMA + y-dot (R7) ----
        floatx4 acc[4];
        #pragma unroll
        for (int g = 0; g < 4; ++g) acc[g] = (floatx4){0.f, 0.f, 0.f, 0.f};
        float p = 0.f;
        uintx4 A[3][2];
        frag_issue<LOC>(A[0][0], A[0][1], fb + 0 * 512);
        frag_issue<LOC>(A[1][0], A[1][1], fb + 1 * 512);
        #pragma unroll
        for (int kt = 0; kt < 8; ++kt) {
            const int sl = kt % 3;
            uintx4& a0 = A[sl][0];
            uintx4& a1 = A[sl][1];
            if (kt < 7) frag_wait2(a0, a1); else frag_wait0(a0, a1);
            pack16 ph, pl;
            ph.u[0] = __builtin_amdgcn_perm(a0[1], a0[0], 0x07060302u);
            ph.u[1] = __builtin_amdgcn_perm(a0[3], a0[2], 0x07060302u);
            ph.u[2] = __builtin_amdgcn_perm(a1[1], a1[0], 0x07060302u);
            ph.u[3] = __builtin_amdgcn_perm(a1[3], a1[2], 0x07060302u);
            pl.u[0] = __builtin_amdgcn_perm(a0[1], a0[0], 0x05040100u);
            pl.u[1] = __builtin_amdgcn_perm(a0[3], a0[2], 0x05040100u);
            pl.u[2] = __builtin_amdgcn_perm(a1[1], a1[0], 0x05040100u);
            pl.u[3] = __builtin_amdgcn_perm(a1[3], a1[2], 0x05040100u);
            if (fc && uc == 0) {
                const float* w = fcw_l + kt * 32 + quad * 8;
                const float4 w0 = *(const float4*)(w);
                const float4 w1 = *(const float4*)(w + 4);
                p += w0.x * (bf2f(ph.v[0]) + bf2f(pl.v[0]));
                p += w0.y * (bf2f(ph.v[1]) + bf2f(pl.v[1]));
                p += w0.z * (bf2f(ph.v[2]) + bf2f(pl.v[2]));
                p += w0.w * (bf2f(ph.v[3]) + bf2f(pl.v[3]));
                p += w1.x * (bf2f(ph.v[4]) + bf2f(pl.v[4]));
                p += w1.y * (bf2f(ph.v[5]) + bf2f(pl.v[5]));
                p += w1.z * (bf2f(ph.v[6]) + bf2f(pl.v[6]));
                p += w1.w * (bf2f(ph.v[7]) + bf2f(pl.v[7]));
            }
            #pragma unroll
            for (int g = 0; g < 4; ++g) {
                bf16x8 bl = *(const bf16x8*)(wlo_s + ((uc * 4 + g) * 8 + kt) * 512 + lane * 8);
                acc[g] = __builtin_amdgcn_mfma_f32_16x16x32_bf16(ph.v, bhi[g][kt], acc[g], 0, 0, 0);
                acc[g] = __builtin_amdgcn_mfma_f32_16x16x32_bf16(pl.v, bhi[g][kt], acc[g], 0, 0, 0);
                acc[g] = __builtin_amdgcn_mfma_f32_16x16x32_bf16(ph.v, bl,        acc[g], 0, 0, 0);
            }
            if (kt < 6)
                frag_issue<LOC>(A[(kt + 2) % 3][0], A[(kt + 2) % 3][1],
                                fb + (kt + 2) * 512);
        }

        if (fc) {               // y(t-1) exchange within block (single-writer)
            if (uc == 0) {
                p += __shfl_xor(p, 16);
                p += __shfl_xor(p, 32);
                if (lane < 16) y_s[rt * 16 + lane] = p;
            }
            __syncthreads();
            if (t >= WARM + 1 && s == 0 && tid < 64)
                out[(rg * 64 + tid) * FLEN + (t - (WARM + 1))] = y_s[tid] + fcb0;
        } else {
            // vmcnt is 0 after kt=7's wait; tie xvv so its consumers stay here
            asm volatile("s_waitcnt vmcnt(0)" : "+v"(xvv) :: "memory");
        }

        // ---- elementwise LSTM + h store (R7 verbatim) ----
        uint* __restrict__ hdst = hg + (size_t)(1u - par) * HG_PAR + (size_t)rg * 16384;
        upk4 xcv; xcv.u = xvv;
        const float xin[4] = {xcv.f.x, xcv.f.y, xcv.f.z, xcv.f.w};
        #pragma unroll
        for (int i = 0; i < 4; ++i) {
            const int rlow = quad * 4 + i;
            float inr = fc ? (y_s[rt * 16 + rlow] + fcb0) : xin[i];
            float gi = acc[0][i] + bbg[0] + inr * wig[0];
            float gf = acc[1][i] + bbg[1] + inr * wig[1];
            float gg = acc[2][i] + bbg[2] + inr * wig[2];
            float go = acc[3][i] + bbg[3] + inr * wig[3];
            float cn = fast_sig(gf) * c[i] + fast_sig(gi) * fast_tanh(gg);
            c[i] = cn;
            float h = fast_sig(go) * fast_tanh(cn);
            short hi = f2bf(h);
            short lo = f2bf(h - bf2f(hi));
            const uint hval = ((uint)(unsigned short)hi << 16) | (uint)(unsigned short)lo;
            uint* hp = hdst + ((((rt * 8 + s) * 4 + kq_u) * 16 + rlow) * 8 + kk_u);
            if (LOC)    // write-through L1 -> lands (and stays) in shared L2
                __hip_atomic_store(hp, hval, __ATOMIC_RELAXED, __HIP_MEMORY_SCOPE_WORKGROUP);
            else
                store_llc32(hp, hval);
        }
        asm volatile("s_waitcnt vmcnt(0)" ::: "memory");   // h stores acked
        __syncthreads();                                    // whole block done

        // ---- inter-block step barrier: R7-verbatim agent-scope LLC path ----
        if (tid == 0) {
            __hip_atomic_fetch_add(&bar[rg * 64], 1u, __ATOMIC_RELAXED,
                                   __HIP_MEMORY_SCOPE_AGENT);
            const uint target = 8u * (uint)(t + 1);
            while (__hip_atomic_load(&bar[rg * 64], __ATOMIC_RELAXED,
                                     __HIP_MEMORY_SCOPE_AGENT) < target)
                __builtin_amdgcn_s_sleep(1);
        }
        __syncthreads();
    }
}

__global__ void __launch_bounds__(512, 2) lstm_main(
    const float* __restrict__ c0, unsigned char* __restrict__ ws,
    const float* __restrict__ fcw, const float* __restrict__ fcb,
    float* __restrict__ out)
{
    extern __shared__ char smem[];
    short* wlo_s = (short*)smem;                  // 32768 shorts (64 KB)
    float* fcw_l = (float*)(smem + 65536);        // 256 floats (1 KB)
    float* y_s   = (float*)(smem + 66560);        // 64 floats

    const int tid  = threadIdx.x;
    const int blk  = blockIdx.x;
    const int rg   = blk & 31;                    // row-group: 64 rows
    const int s    = blk >> 5;                    // unit-slice: 32 units
    const int wv   = tid >> 6, lane = tid & 63;
    const int quad = lane >> 4, nof = lane & 15;
    const int uc   = wv & 1, rt = wv >> 1;        // wave = (row-tile rt, unit-chunk uc)

    const short* whi_g = (const short*)(ws + WHI_OFF);
    const float* bb    = (const float*)(ws + BB_OFF);
    const float* wi    = (const float*)(ws + WI_OFF);
    const float* xT    = (const float*)(ws + XT_OFF);
    uint* bar          = (uint*)(ws + BAR_OFF);
    uint* hg           = (uint*)(ws + HG_OFF);

    // ---- stage W-lo slice -> LDS (64 KB contiguous) + fcw -> LDS ----
    {
        const uint4* src = (const uint4*)(ws + WLO_OFF) + (size_t)s * 4096;
        uint4* dst = (uint4*)wlo_s;
        for (int i = tid; i < 4096; i += 512) dst[i] = src[i];
        if (tid < 256) fcw_l[tid] = fcw[tid];
    }
    // ---- W-hi fragments -> registers/AGPRs (32 x 16B per lane) ----
    bf16x8 bhi[4][8];
    {
        const bf16x8* src = (const bf16x8*)whi_g;
        #pragma unroll
        for (int g = 0; g < 4; ++g)
            #pragma unroll
            for (int kt = 0; kt < 8; ++kt)
                bhi[g][kt] = src[(size_t)(((s * 2 + uc) * 4 + g) * 8 + kt) * 64 + lane];
    }

    // ---- per-thread constants ----
    const int u = s * 32 + uc * 16 + nof;         // owned hidden unit (elementwise)
    float bbg[4], wig[4];
    #pragma unroll
    for (int g = 0; g < 4; ++g) { bbg[g] = bb[g * 256 + u]; wig[g] = wi[g * 256 + u]; }
    const float fcb0 = fcb[0];
    float c[4];
    #pragma unroll
    for (int i = 0; i < 4; ++i)
        c[i] = c0[(rg * 64 + rt * 16 + quad * 4 + i) * HDIM + u];
    const int kq_u = uc * 2 + (nof >> 3);
    const int kk_u = nof & 7;

    // ---- XCD co-location check: rg-uniform verdict; fallback = LLC ----
    if (tid == 0) {
        store_llc32(&bar[rg * 64 + 32 + s], get_xcc_id() + 1u);
        asm volatile("s_waitcnt vmcnt(0)" ::: "memory");
        __hip_atomic_fetch_add(&bar[rg * 64 + 16], 1u, __ATOMIC_RELAXED,
                               __HIP_MEMORY_SCOPE_AGENT);
        while (__hip_atomic_load(&bar[rg * 64 + 16], __ATOMIC_RELAXED,
                                 __HIP_MEMORY_SCOPE_AGENT) < 8u)
            __builtin_amdgcn_s_sleep(1);
        const uint x0 = load_llc32u(&bar[rg * 64 + 32]);
        int ok = 1;
        #pragma unroll
        for (int j = 1; j < 8; ++j)
            ok &= (load_llc32u(&bar[rg * 64 + 32 + j]) == x0);
        ((int*)y_s)[0] = ok;
    }
    __syncthreads();
    const int l2loc = ((int*)y_s)[0];
    __syncthreads();    // verdict consumed before y_s is reused

    if (l2loc)
        run_steps<true>(wlo_s, fcw_l, y_s, xT, bar, hg, out, bhi, c,
                        bbg, wig, fcb0, tid, rg, s, lane, quad, uc, rt,
                        kq_u, kk_u);
    else
        run_steps<false>(wlo_s, fcw_l, y_s, xT, bar, hg, out, bhi, c,
                         bbg, wig, fcb0, tid, rg, s, lane, quad, uc, rt,
                         kq_u, kk_u);
}

extern "C" void kernel_launch(void* const* d_in, const int* in_sizes, int n_in,
                              void* d_out, int out_size, void* d_ws, size_t ws_size,
                              hipStream_t stream) {
    const float* x    = (const float*)d_in[0];
    const float* h0   = (const float*)d_in[1];
    const float* c0   = (const float*)d_in[2];
    const float* W_ih = (const float*)d_in[3];
    const float* W_hh = (const float*)d_in[4];
    const float* b_ih = (const float*)d_in[5];
    const float* b_hh = (const float*)d_in[6];
    const float* fc_w = (const float*)d_in[7];
    const float* fc_b = (const float*)d_in[8];
    float* out = (float*)d_out;
    unsigned char* ws = (unsigned char*)d_ws;

    lstm_prep<<<2048, 256, 0, stream>>>(W_ih, W_hh, b_ih, b_hh, h0, x, ws);

    static int attr_set = 0;
    if (!attr_set) {
        (void)hipFuncSetAttribute((const void*)lstm_main,
                                  hipFuncAttributeMaxDynamicSharedMemorySize, LDS_BYTES);
        attr_set = 1;
    }
    void* args[] = {(void*)&c0, (void*)&ws, (void*)&fc_w, (void*)&fc_b, (void*)&out};
    (void)hipLaunchCooperativeKernel((const void*)lstm_main, dim3(256), dim3(512),
                                     args, LDS_BYTES, stream);
}